// Round 1
// baseline (696.625 us; speedup 1.0000x reference)
//
#include <hip/hip_runtime.h>

// EdgeNetwork: out[a] = sum over edges e with dst(e)==a of
//   (bond[e] @ kernel + bias).reshape(16,16) @ atom[src(e)]
// Fused: never materialize the E x 256 bond_mats (655 MB).
// msg[i] = sum_k bond[k] * ( sum_j K[k][i*16+j] * neigh[j] )  + sum_j bias[i*16+j]*neigh[j]
// K/bias are wave-uniform -> compiler promotes to s_load, FMAs take SGPR operand.

constexpr int DIM = 16;

__global__ __launch_bounds__(256) void edge_msg_kernel(
    const float* __restrict__ atom,
    const float* __restrict__ bond,
    const int*   __restrict__ pair,
    const float* __restrict__ kern,
    const float* __restrict__ bias,
    float*       __restrict__ out,
    int n_edges)
{
    int e = blockIdx.x * blockDim.x + threadIdx.x;
    if (e >= n_edges) return;

    const int dst = pair[2 * e + 0];
    const int src = pair[2 * e + 1];

    // neighbor features (random gather; atom table is 1.28 MB -> L2-resident)
    float neigh[DIM];
    {
        const float4* ap = (const float4*)(atom + (size_t)src * DIM);
        float4 v0 = ap[0], v1 = ap[1], v2 = ap[2], v3 = ap[3];
        neigh[0]=v0.x; neigh[1]=v0.y; neigh[2]=v0.z; neigh[3]=v0.w;
        neigh[4]=v1.x; neigh[5]=v1.y; neigh[6]=v1.z; neigh[7]=v1.w;
        neigh[8]=v2.x; neigh[9]=v2.y; neigh[10]=v2.z; neigh[11]=v2.w;
        neigh[12]=v3.x; neigh[13]=v3.y; neigh[14]=v3.z; neigh[15]=v3.w;
    }

    // this edge's bond features (coalesced-ish: 16B chunks, all bytes used)
    float bnd[DIM];
    {
        const float4* bp = (const float4*)(bond + (size_t)e * DIM);
        float4 v0 = bp[0], v1 = bp[1], v2 = bp[2], v3 = bp[3];
        bnd[0]=v0.x; bnd[1]=v0.y; bnd[2]=v0.z; bnd[3]=v0.w;
        bnd[4]=v1.x; bnd[5]=v1.y; bnd[6]=v1.z; bnd[7]=v1.w;
        bnd[8]=v2.x; bnd[9]=v2.y; bnd[10]=v2.z; bnd[11]=v2.w;
        bnd[12]=v3.x; bnd[13]=v3.y; bnd[14]=v3.z; bnd[15]=v3.w;
    }

    // bias term: acc[i] = dot(bias[i*16 .. +16], neigh)   (bias is uniform -> s_load)
    float acc[DIM];
#pragma unroll
    for (int i = 0; i < DIM; ++i) {
        float d = 0.f;
#pragma unroll
        for (int j = 0; j < DIM; ++j) d = fmaf(bias[i * DIM + j], neigh[j], d);
        acc[i] = d;
    }

    // main contraction; k-loop rolled to keep body ~272 FMAs (I$-friendly)
#pragma unroll 1
    for (int k = 0; k < DIM; ++k) {
        const float bk = bnd[k];
        const float* __restrict__ Kr = kern + k * (DIM * DIM);
#pragma unroll
        for (int i = 0; i < DIM; ++i) {
            float d = 0.f;
#pragma unroll
            for (int j = 0; j < DIM; ++j) d = fmaf(Kr[i * DIM + j], neigh[j], d);
            acc[i] = fmaf(bk, d, acc[i]);
        }
    }

    // scatter-add into destination atom (random dst, ~32 edges/atom)
    const size_t ob = (size_t)dst * DIM;
#pragma unroll
    for (int i = 0; i < DIM; ++i) atomicAdd(&out[ob + i], acc[i]);
}

extern "C" void kernel_launch(void* const* d_in, const int* in_sizes, int n_in,
                              void* d_out, int out_size, void* d_ws, size_t ws_size,
                              hipStream_t stream)
{
    const float* atom = (const float*)d_in[0];   // (20000,16) f32
    const float* bond = (const float*)d_in[1];   // (640000,16) f32
    const int*   pair = (const int*)d_in[2];     // (640000,2) i32 [dst, src]
    const float* kern = (const float*)d_in[3];   // (16,256) f32
    const float* bias = (const float*)d_in[4];   // (256,) f32
    float*       out  = (float*)d_out;           // (20000,16) f32

    const int n_edges = in_sizes[1] / DIM;       // 640000

    // harness poisons d_out with 0xAA before every timed call -> zero it
    hipMemsetAsync(out, 0, (size_t)out_size * sizeof(float), stream);

    const int threads = 256;
    const int blocks  = (n_edges + threads - 1) / threads;
    edge_msg_kernel<<<blocks, threads, 0, stream>>>(atom, bond, pair, kern, bias,
                                                    out, n_edges);
}

// Round 2
// 332.890 us; speedup vs baseline: 2.0927x; 2.0927x over previous
//
#include <hip/hip_runtime.h>

// EdgeNetwork fused + CSR two-phase to eliminate f32 atomics.
// out[a] = sum_{e: dst(e)==a} (bond[e] @ K + bias).reshape(16,16) @ atom[src(e)]
//
// Round-1 lesson (rocprof): 10.24M f32 atomicAdds -> WRITE_SIZE 327 MB
// (32 B HBM write-through per device-scope atomic) + per-line serialization
// (~512 atomics/atom line) -> 630 us. This version builds a CSR on device
// each call (640K int atomics only) and does an atomic-free segmented sum.

constexpr int DIM     = 16;
constexpr int SCAN_BS = 1024;

__device__ __forceinline__ void compute_msg(
    const float* __restrict__ atom,
    const float* __restrict__ bond,
    const float* __restrict__ kern,
    const float* __restrict__ bias,
    int e, int src, float acc[DIM])
{
    float neigh[DIM];
    {
        const float4* ap = (const float4*)(atom + (size_t)src * DIM);
        float4 v0 = ap[0], v1 = ap[1], v2 = ap[2], v3 = ap[3];
        neigh[0]=v0.x; neigh[1]=v0.y; neigh[2]=v0.z; neigh[3]=v0.w;
        neigh[4]=v1.x; neigh[5]=v1.y; neigh[6]=v1.z; neigh[7]=v1.w;
        neigh[8]=v2.x; neigh[9]=v2.y; neigh[10]=v2.z; neigh[11]=v2.w;
        neigh[12]=v3.x; neigh[13]=v3.y; neigh[14]=v3.z; neigh[15]=v3.w;
    }
    float bnd[DIM];
    {
        const float4* bp = (const float4*)(bond + (size_t)e * DIM);
        float4 v0 = bp[0], v1 = bp[1], v2 = bp[2], v3 = bp[3];
        bnd[0]=v0.x; bnd[1]=v0.y; bnd[2]=v0.z; bnd[3]=v0.w;
        bnd[4]=v1.x; bnd[5]=v1.y; bnd[6]=v1.z; bnd[7]=v1.w;
        bnd[8]=v2.x; bnd[9]=v2.y; bnd[10]=v2.z; bnd[11]=v2.w;
        bnd[12]=v3.x; bnd[13]=v3.y; bnd[14]=v3.z; bnd[15]=v3.w;
    }

    // bias term: acc[i] = dot(bias[i*16..], neigh)  (bias uniform -> SGPR)
#pragma unroll
    for (int i = 0; i < DIM; ++i) {
        float d = 0.f;
#pragma unroll
        for (int j = 0; j < DIM; ++j) d = fmaf(bias[i * DIM + j], neigh[j], d);
        acc[i] = d;
    }
    // main contraction; K uniform -> SGPR operands. Keep k-loop rolled.
#pragma unroll 1
    for (int k = 0; k < DIM; ++k) {
        const float bk = bnd[k];
        const float* __restrict__ Kr = kern + k * (DIM * DIM);
#pragma unroll
        for (int i = 0; i < DIM; ++i) {
            float d = 0.f;
#pragma unroll
            for (int j = 0; j < DIM; ++j) d = fmaf(Kr[i * DIM + j], neigh[j], d);
            acc[i] = fmaf(bk, d, acc[i]);
        }
    }
}

// ---- Phase 1: rank[e] = arrival order within dst; counts[] doubles as histogram
__global__ __launch_bounds__(256) void rank_kernel(
    const int* __restrict__ pair, int* __restrict__ counts,
    int* __restrict__ rank, int n_edges)
{
    int e = blockIdx.x * blockDim.x + threadIdx.x;
    if (e >= n_edges) return;
    int dst = pair[2 * e];
    rank[e] = atomicAdd(&counts[dst], 1);
}

// ---- Phase 2: exclusive scan of counts (single block, chunked Hillis-Steele)
__global__ __launch_bounds__(SCAN_BS) void scan_kernel(
    const int* __restrict__ counts, int* __restrict__ offsets, int n)
{
    __shared__ int lds[SCAN_BS];
    const int tid = threadIdx.x;
    int run = 0;
    for (int base = 0; base < n; base += SCAN_BS) {
        int idx = base + tid;
        int v = (idx < n) ? counts[idx] : 0;
        lds[tid] = v;
        __syncthreads();
#pragma unroll
        for (int off = 1; off < SCAN_BS; off <<= 1) {
            int t = (tid >= off) ? lds[tid - off] : 0;
            __syncthreads();
            if (tid >= off) lds[tid] += t;
            __syncthreads();
        }
        if (idx < n) offsets[idx] = run + lds[tid] - v;   // exclusive
        run += lds[SCAN_BS - 1];                          // uniform across threads
        __syncthreads();
    }
    if (tid == 0) offsets[n] = run;
}

// ---- Phase 3: fused compute, write message into its sorted slot (no atomics)
__global__ __launch_bounds__(256) void msg_kernel(
    const float* __restrict__ atom, const float* __restrict__ bond,
    const int*   __restrict__ pair, const float* __restrict__ kern,
    const float* __restrict__ bias, const int* __restrict__ offsets,
    const int*   __restrict__ rank, float* __restrict__ msgs, int n_edges)
{
    int e = blockIdx.x * blockDim.x + threadIdx.x;
    if (e >= n_edges) return;
    int dst = pair[2 * e + 0];
    int src = pair[2 * e + 1];

    float acc[DIM];
    compute_msg(atom, bond, kern, bias, e, src, acc);

    const size_t slot = (size_t)(offsets[dst] + rank[e]) * DIM;
    float4* mp = (float4*)(msgs + slot);   // 64B-aligned line store
    mp[0] = make_float4(acc[0],  acc[1],  acc[2],  acc[3]);
    mp[1] = make_float4(acc[4],  acc[5],  acc[6],  acc[7]);
    mp[2] = make_float4(acc[8],  acc[9],  acc[10], acc[11]);
    mp[3] = make_float4(acc[12], acc[13], acc[14], acc[15]);
}

// ---- Phase 4: segmented sum over contiguous per-atom segments.
// 8 threads per atom: c = tid%4 selects float4 chunk, half = (tid/4)%2 splits
// the edge list; partner lanes combine via shfl_xor(4). Coalesced, atomic-free.
__global__ __launch_bounds__(256) void reduce_kernel(
    const float* __restrict__ msgs, const int* __restrict__ offsets,
    float* __restrict__ out, int n_atoms)
{
    int t = blockIdx.x * blockDim.x + threadIdx.x;
    int a = t >> 3;
    if (a >= n_atoms) return;
    int c    = t & 3;
    int half = (t >> 2) & 1;

    int beg = offsets[a];
    int end = offsets[a + 1];

    float4 acc = make_float4(0.f, 0.f, 0.f, 0.f);
    const float4* mp = (const float4*)msgs;
    for (int j = beg + half; j < end; j += 2) {
        float4 v = mp[(size_t)j * 4 + c];
        acc.x += v.x; acc.y += v.y; acc.z += v.z; acc.w += v.w;
    }
    // combine halves: partner is lane ^ 4
    acc.x += __shfl_xor(acc.x, 4);
    acc.y += __shfl_xor(acc.y, 4);
    acc.z += __shfl_xor(acc.z, 4);
    acc.w += __shfl_xor(acc.w, 4);
    if (half == 0) {
        ((float4*)(out + (size_t)a * DIM))[c] = acc;
    }
}

// ---- Fallback (round-1 atomic version) if ws is too small
__global__ __launch_bounds__(256) void edge_atomic_kernel(
    const float* __restrict__ atom, const float* __restrict__ bond,
    const int*   __restrict__ pair, const float* __restrict__ kern,
    const float* __restrict__ bias, float* __restrict__ out, int n_edges)
{
    int e = blockIdx.x * blockDim.x + threadIdx.x;
    if (e >= n_edges) return;
    int dst = pair[2 * e + 0];
    int src = pair[2 * e + 1];
    float acc[DIM];
    compute_msg(atom, bond, kern, bias, e, src, acc);
    const size_t ob = (size_t)dst * DIM;
#pragma unroll
    for (int i = 0; i < DIM; ++i) atomicAdd(&out[ob + i], acc[i]);
}

extern "C" void kernel_launch(void* const* d_in, const int* in_sizes, int n_in,
                              void* d_out, int out_size, void* d_ws, size_t ws_size,
                              hipStream_t stream)
{
    const float* atom = (const float*)d_in[0];   // (20000,16) f32
    const float* bond = (const float*)d_in[1];   // (640000,16) f32
    const int*   pair = (const int*)d_in[2];     // (640000,2) i32 [dst, src]
    const float* kern = (const float*)d_in[3];   // (16,256) f32
    const float* bias = (const float*)d_in[4];   // (256,) f32
    float*       out  = (float*)d_out;           // (20000,16) f32

    const int n_edges = in_sizes[1] / DIM;       // 640000
    const int n_atoms = in_sizes[0] / DIM;       // 20000

    // ws layout: counts[A] | offsets[A+1] | rank[E] | (64B align) msgs[E*16]
    size_t counts_off = 0;
    size_t offsets_off = counts_off + (size_t)n_atoms * sizeof(int);
    size_t rank_off    = offsets_off + (size_t)(n_atoms + 1) * sizeof(int);
    size_t msgs_off    = (rank_off + (size_t)n_edges * sizeof(int) + 63) & ~(size_t)63;
    size_t needed      = msgs_off + (size_t)n_edges * DIM * sizeof(float);

    const int threads = 256;
    const int eblocks = (n_edges + threads - 1) / threads;

    if (ws_size >= needed) {
        int*   counts  = (int*)((char*)d_ws + counts_off);
        int*   offsets = (int*)((char*)d_ws + offsets_off);
        int*   rank    = (int*)((char*)d_ws + rank_off);
        float* msgs    = (float*)((char*)d_ws + msgs_off);

        hipMemsetAsync(counts, 0, (size_t)n_atoms * sizeof(int), stream);
        rank_kernel<<<eblocks, threads, 0, stream>>>(pair, counts, rank, n_edges);
        scan_kernel<<<1, SCAN_BS, 0, stream>>>(counts, offsets, n_atoms);
        msg_kernel<<<eblocks, threads, 0, stream>>>(atom, bond, pair, kern, bias,
                                                    offsets, rank, msgs, n_edges);
        const int rthreads = n_atoms * 8;
        reduce_kernel<<<(rthreads + threads - 1) / threads, threads, 0, stream>>>(
            msgs, offsets, out, n_atoms);
    } else {
        // fallback: atomic scatter (round-1 behavior)
        hipMemsetAsync(out, 0, (size_t)out_size * sizeof(float), stream);
        edge_atomic_kernel<<<eblocks, threads, 0, stream>>>(atom, bond, pair, kern,
                                                            bias, out, n_edges);
    }
}

// Round 3
// 190.559 us; speedup vs baseline: 3.6557x; 1.7469x over previous
//
#include <hip/hip_runtime.h>
#include <stdint.h>

// EdgeNetwork, round 3: msgs(E x 16) = Z(E x 256) @ W(256 x 16) via bf16 MFMA.
//   Z[e, kb*16+j] = bond[e,kb] * neigh[e,j]   (built on the fly in A-frag layout)
//   W[kb*16+j, i] = K[kb][i*16+j];  bias folded in as a 17th chunk (z=neigh).
// CSR (rank/scan) from round 2 kept: it removed the 327 MB atomic write-through.
// Round-2 lesson: per-thread scalar matvec stalls on s_load of K (21% VALUBusy);
// this is a GEMM -> use the matrix pipe.

constexpr int DIM = 16;
constexpr int GPW = 8;        // 16-edge groups per wave in msg kernel
constexpr int SCAN_BS = 1024;

using frag_ab = __attribute__((ext_vector_type(8))) short;   // 8 bf16
using frag_cd = __attribute__((ext_vector_type(4))) float;   // 4 f32

union ABPack { frag_ab f; uint32_t u[4]; };

__device__ __forceinline__ uint32_t pack_bf16_2(float lo, float hi) {
    // truncate-to-bf16, two f32 -> one dword (lo in low 16 bits)
    return (__float_as_uint(hi) & 0xFFFF0000u) | (__float_as_uint(lo) >> 16);
}

// ---- Phase 1: rank[e] = arrival order within dst; counts doubles as histogram
__global__ __launch_bounds__(256) void rank_kernel(
    const int* __restrict__ pair, int* __restrict__ counts,
    int* __restrict__ rank, int n_edges)
{
    int e = blockIdx.x * blockDim.x + threadIdx.x;
    if (e >= n_edges) return;
    rank[e] = atomicAdd(&counts[pair[2 * e]], 1);
}

// ---- Phase 2: exclusive scan, single block, wave-shfl based (3 barriers/chunk)
__global__ __launch_bounds__(SCAN_BS) void scan_kernel(
    const int* __restrict__ counts, int* __restrict__ offsets, int n)
{
    __shared__ int wex[16];        // exclusive prefix of wave sums
    __shared__ int ctot;           // chunk total
    const int tid  = threadIdx.x;
    const int lane = tid & 63;
    const int w    = tid >> 6;
    int run = 0;
    for (int base = 0; base < n; base += SCAN_BS) {
        int idx = base + tid;
        int v = (idx < n) ? counts[idx] : 0;
        int s = v;                                   // inclusive wave scan
#pragma unroll
        for (int off = 1; off < 64; off <<= 1) {
            int t = __shfl_up(s, off, 64);
            if (lane >= off) s += t;
        }
        if (lane == 63) wex[w] = s;                  // wave sum
        __syncthreads();
        if (w == 0 && lane < 16) {
            int orig = wex[lane];
            int ws = orig;
#pragma unroll
            for (int off = 1; off < 16; off <<= 1) {
                int t = __shfl_up(ws, off, 64);
                if (lane >= off) ws += t;
            }
            wex[lane] = ws - orig;                   // exclusive
            if (lane == 15) ctot = ws;
        }
        __syncthreads();
        if (idx < n) offsets[idx] = run + wex[w] + s - v;
        run += ctot;
        __syncthreads();                             // protect wex/ctot reuse
    }
    if (tid == 0) offsets[n] = run;
}

// ---- Phase 3: MFMA message kernel, writes each message to its sorted slot
__global__ __launch_bounds__(256) void msg_mfma_kernel(
    const float* __restrict__ atom, const float* __restrict__ bond,
    const int*   __restrict__ pair, const float* __restrict__ kern,
    const float* __restrict__ bias, const int* __restrict__ offsets,
    const int*   __restrict__ rank, float* __restrict__ msgs,
    int n_edges, int n_groups)
{
    const int wave = (int)((blockIdx.x * blockDim.x + threadIdx.x) >> 6);
    const int lane = threadIdx.x & 63;
    int g0 = wave * GPW;
    if (g0 >= n_groups) return;
    int g1 = min(g0 + GPW, n_groups);

    const int col  = lane & 15;        // A: edge m | B/D: output col i
    const int quad = lane >> 4;        // 0..3
    const int hb   = quad >> 1;        // kb parity within chunk
    const int j0   = (quad & 1) * 8;   // neigh sub-range

    // B fragments (kernel matrix), edge-invariant: load once per wave.
    // lane holds W[k_local][col] for k_local = quad*8 + jj;
    // kb = 2*chunk + hb, j = j0 + jj -> K[kb][col*16 + j0 + jj], 8 consecutive.
    frag_ab bfrag[8];
#pragma unroll
    for (int c = 0; c < 8; ++c) {
        const float* wp = kern + (2 * c + hb) * 256 + col * 16 + j0;
        float4 w0 = *(const float4*)wp;
        float4 w1 = *(const float4*)(wp + 4);
        ABPack p;
        p.u[0] = pack_bf16_2(w0.x, w0.y);
        p.u[1] = pack_bf16_2(w0.z, w0.w);
        p.u[2] = pack_bf16_2(w1.x, w1.y);
        p.u[3] = pack_bf16_2(w1.z, w1.w);
        bfrag[c] = p.f;
    }
    // bias chunk B-frag: k_local<16 half only (hb==0), zero otherwise
    frag_ab bias_b;
    {
        ABPack p; p.u[0] = p.u[1] = p.u[2] = p.u[3] = 0;
        if (hb == 0) {
            const float* bp2 = bias + col * 16 + j0;
            float4 w0 = *(const float4*)bp2;
            float4 w1 = *(const float4*)(bp2 + 4);
            p.u[0] = pack_bf16_2(w0.x, w0.y);
            p.u[1] = pack_bf16_2(w0.z, w0.w);
            p.u[2] = pack_bf16_2(w1.x, w1.y);
            p.u[3] = pack_bf16_2(w1.z, w1.w);
        }
        bias_b = p.f;
    }

    for (int g = g0; g < g1; ++g) {
        const int eb = g << 4;
        const int e  = eb + col;
        const int ec = min(e, n_edges - 1);

        const int2 pr  = ((const int2*)pair)[ec];           // x=dst, y=src
        const int slot = offsets[pr.x] + rank[ec];

        // neigh slice: chunk-invariant 8 floats [j0, j0+8)
        const float* np_ = atom + (size_t)pr.y * DIM + j0;
        float4 n0 = *(const float4*)np_;
        float4 n1 = *(const float4*)(np_ + 4);
        float nb[8] = {n0.x, n0.y, n0.z, n0.w, n1.x, n1.y, n1.z, n1.w};

        // bond row: 16 floats (4 lanes share the line -> coalesced)
        const float4* bp = (const float4*)(bond + (size_t)ec * DIM);
        float4 b0 = bp[0], b1 = bp[1], b2 = bp[2], b3 = bp[3];
        float bv[16] = {b0.x, b0.y, b0.z, b0.w, b1.x, b1.y, b1.z, b1.w,
                        b2.x, b2.y, b2.z, b2.w, b3.x, b3.y, b3.z, b3.w};

        frag_cd acc = {0.f, 0.f, 0.f, 0.f};
#pragma unroll
        for (int c = 0; c < 8; ++c) {
            const float bk = bv[2 * c + hb];
            ABPack a;
            a.u[0] = pack_bf16_2(bk * nb[0], bk * nb[1]);
            a.u[1] = pack_bf16_2(bk * nb[2], bk * nb[3]);
            a.u[2] = pack_bf16_2(bk * nb[4], bk * nb[5]);
            a.u[3] = pack_bf16_2(bk * nb[6], bk * nb[7]);
            acc = __builtin_amdgcn_mfma_f32_16x16x32_bf16(a.f, bfrag[c], acc, 0, 0, 0);
        }
        { // bias chunk: A = neigh on k_local<16, zero above
            ABPack a; a.u[0] = a.u[1] = a.u[2] = a.u[3] = 0;
            if (hb == 0) {
                a.u[0] = pack_bf16_2(nb[0], nb[1]);
                a.u[1] = pack_bf16_2(nb[2], nb[3]);
                a.u[2] = pack_bf16_2(nb[4], nb[5]);
                a.u[3] = pack_bf16_2(nb[6], nb[7]);
            }
            acc = __builtin_amdgcn_mfma_f32_16x16x32_bf16(a.f, bias_b, acc, 0, 0, 0);
        }

        // D: lane holds rows m = quad*4+r, col = output i. slot lives in lane m.
#pragma unroll
        for (int r = 0; r < 4; ++r) {
            const int m  = quad * 4 + r;
            const int er = eb + m;
            const int s  = __shfl(slot, m, 64);
            if (er < n_edges)
                msgs[(size_t)s * DIM + col] = acc[r];
        }
    }
}

// ---- Phase 4: segmented sum over contiguous per-atom segments (atomic-free)
__global__ __launch_bounds__(256) void reduce_kernel(
    const float* __restrict__ msgs, const int* __restrict__ offsets,
    float* __restrict__ out, int n_atoms)
{
    int t = blockIdx.x * blockDim.x + threadIdx.x;
    int a = t >> 3;
    if (a >= n_atoms) return;
    int c    = t & 3;
    int half = (t >> 2) & 1;

    int beg = offsets[a];
    int end = offsets[a + 1];

    float4 acc = make_float4(0.f, 0.f, 0.f, 0.f);
    const float4* mp = (const float4*)msgs;
    for (int j = beg + half; j < end; j += 2) {
        float4 v = mp[(size_t)j * 4 + c];
        acc.x += v.x; acc.y += v.y; acc.z += v.z; acc.w += v.w;
    }
    acc.x += __shfl_xor(acc.x, 4);
    acc.y += __shfl_xor(acc.y, 4);
    acc.z += __shfl_xor(acc.z, 4);
    acc.w += __shfl_xor(acc.w, 4);
    if (half == 0)
        ((float4*)(out + (size_t)a * DIM))[c] = acc;
}

// ---- Fallback (atomic scatter) if ws too small — round-1 structure
__global__ __launch_bounds__(256) void edge_atomic_kernel(
    const float* __restrict__ atom, const float* __restrict__ bond,
    const int*   __restrict__ pair, const float* __restrict__ kern,
    const float* __restrict__ bias, float* __restrict__ out, int n_edges)
{
    int e = blockIdx.x * blockDim.x + threadIdx.x;
    if (e >= n_edges) return;
    int dst = pair[2 * e + 0];
    int src = pair[2 * e + 1];
    float neigh[DIM], bnd[DIM], acc2[DIM];
    const float4* ap = (const float4*)(atom + (size_t)src * DIM);
    const float4* bp = (const float4*)(bond + (size_t)e * DIM);
    for (int i = 0; i < 4; ++i) {
        float4 v = ap[i];
        neigh[4*i] = v.x; neigh[4*i+1] = v.y; neigh[4*i+2] = v.z; neigh[4*i+3] = v.w;
        float4 w = bp[i];
        bnd[4*i] = w.x; bnd[4*i+1] = w.y; bnd[4*i+2] = w.z; bnd[4*i+3] = w.w;
    }
#pragma unroll
    for (int i = 0; i < DIM; ++i) {
        float d = 0.f;
#pragma unroll
        for (int j = 0; j < DIM; ++j) d = fmaf(bias[i * DIM + j], neigh[j], d);
        acc2[i] = d;
    }
#pragma unroll 1
    for (int k = 0; k < DIM; ++k) {
        const float bk = bnd[k];
        const float* Kr = kern + k * (DIM * DIM);
#pragma unroll
        for (int i = 0; i < DIM; ++i) {
            float d = 0.f;
#pragma unroll
            for (int j = 0; j < DIM; ++j) d = fmaf(Kr[i * DIM + j], neigh[j], d);
            acc2[i] = fmaf(bk, d, acc2[i]);
        }
    }
    const size_t ob = (size_t)dst * DIM;
#pragma unroll
    for (int i = 0; i < DIM; ++i) atomicAdd(&out[ob + i], acc2[i]);
}

extern "C" void kernel_launch(void* const* d_in, const int* in_sizes, int n_in,
                              void* d_out, int out_size, void* d_ws, size_t ws_size,
                              hipStream_t stream)
{
    const float* atom = (const float*)d_in[0];   // (20000,16) f32
    const float* bond = (const float*)d_in[1];   // (640000,16) f32
    const int*   pair = (const int*)d_in[2];     // (640000,2) i32 [dst, src]
    const float* kern = (const float*)d_in[3];   // (16,256) f32
    const float* bias = (const float*)d_in[4];   // (256,) f32
    float*       out  = (float*)d_out;           // (20000,16) f32

    const int n_edges = in_sizes[1] / DIM;       // 640000
    const int n_atoms = in_sizes[0] / DIM;       // 20000

    size_t counts_off  = 0;
    size_t offsets_off = counts_off + (size_t)n_atoms * sizeof(int);
    size_t rank_off    = offsets_off + (size_t)(n_atoms + 1) * sizeof(int);
    size_t msgs_off    = (rank_off + (size_t)n_edges * sizeof(int) + 63) & ~(size_t)63;
    size_t needed      = msgs_off + (size_t)n_edges * DIM * sizeof(float);

    const int threads = 256;
    const int eblocks = (n_edges + threads - 1) / threads;

    if (ws_size >= needed) {
        int*   counts  = (int*)((char*)d_ws + counts_off);
        int*   offsets = (int*)((char*)d_ws + offsets_off);
        int*   rank    = (int*)((char*)d_ws + rank_off);
        float* msgs    = (float*)((char*)d_ws + msgs_off);

        hipMemsetAsync(counts, 0, (size_t)n_atoms * sizeof(int), stream);
        rank_kernel<<<eblocks, threads, 0, stream>>>(pair, counts, rank, n_edges);
        scan_kernel<<<1, SCAN_BS, 0, stream>>>(counts, offsets, n_atoms);

        const int n_groups = (n_edges + 15) / 16;
        const int waves    = (n_groups + GPW - 1) / GPW;
        const int mblocks  = (waves * 64 + threads - 1) / threads;
        msg_mfma_kernel<<<mblocks, threads, 0, stream>>>(
            atom, bond, pair, kern, bias, offsets, rank, msgs, n_edges, n_groups);

        const int rthreads = n_atoms * 8;
        reduce_kernel<<<(rthreads + threads - 1) / threads, threads, 0, stream>>>(
            msgs, offsets, out, n_atoms);
    } else {
        hipMemsetAsync(out, 0, (size_t)out_size * sizeof(float), stream);
        edge_atomic_kernel<<<eblocks, threads, 0, stream>>>(atom, bond, pair, kern,
                                                            bias, out, n_edges);
    }
}

// Round 4
// 150.136 us; speedup vs baseline: 4.6400x; 1.2692x over previous
//
#include <hip/hip_runtime.h>
#include <stdint.h>

// EdgeNetwork, round 4: fixed-stride binning replaces rank+scan CSR.
//   msgs(E x 16) = Z(E x 256) @ W(256 x 16) via bf16 MFMA (round-3 math, verified)
//   slot = dst*CAP + atomicAdd(counts[dst])  (CAP=64; Poisson(32) degrees)
//   messages stored bf16 (halves msg traffic); overflow edges (~never) fixed up
//   by a scalar atomic kernel after the reduce.
// History: r1 atomic scatter 630us (327MB write-through) -> r2 CSR 333us ->
// r3 MFMA msg 190us (scaffolding dominates) -> r4: kill rank+scan dispatches.

constexpr int DIM       = 16;
constexpr int CAP       = 64;      // slots per atom; P(deg>64) ~ 1e-8 at Poisson(32)
constexpr int OFLOW_CAP = 65536;
constexpr int GPW       = 4;       // 16-edge groups per wave (2500 blocks)

using frag_ab = __attribute__((ext_vector_type(8))) short;   // 8 bf16
using frag_cd = __attribute__((ext_vector_type(4))) float;   // 4 f32
union ABPack { frag_ab f; uint32_t u[4]; };

__device__ __forceinline__ uint32_t pack_bf16_2(float lo, float hi) {
    // one v_perm_b32: [hi.b3, hi.b2, lo.b3, lo.b2] (truncate-to-bf16 pair)
    return __builtin_amdgcn_perm(__float_as_uint(hi), __float_as_uint(lo), 0x07060302u);
}

// ---- msg kernel: fused rank + MFMA + bf16 store into fixed-stride slot
__global__ __launch_bounds__(256) void msg_mfma_kernel(
    const float* __restrict__ atom, const float* __restrict__ bond,
    const int*   __restrict__ pair, const float* __restrict__ kern,
    const float* __restrict__ bias,
    int* __restrict__ counts, int* __restrict__ oflow_cnt, int* __restrict__ oflow,
    uint16_t* __restrict__ msgs, int n_edges, int n_groups)
{
    const int wave = (int)((blockIdx.x * blockDim.x + threadIdx.x) >> 6);
    const int lane = threadIdx.x & 63;
    int g0 = wave * GPW;
    if (g0 >= n_groups) return;
    int g1 = min(g0 + GPW, n_groups);

    const int col  = lane & 15;        // A: edge m | B/D: output col i
    const int quad = lane >> 4;        // 0..3
    const int hb   = quad >> 1;        // kb parity within chunk
    const int j0   = (quad & 1) * 8;   // neigh sub-range

    // B fragments (kernel matrix), edge-invariant (round-3 layout, verified)
    frag_ab bfrag[8];
#pragma unroll
    for (int c = 0; c < 8; ++c) {
        const float* wp = kern + (2 * c + hb) * 256 + col * 16 + j0;
        float4 w0 = *(const float4*)wp;
        float4 w1 = *(const float4*)(wp + 4);
        ABPack p;
        p.u[0] = pack_bf16_2(w0.x, w0.y);
        p.u[1] = pack_bf16_2(w0.z, w0.w);
        p.u[2] = pack_bf16_2(w1.x, w1.y);
        p.u[3] = pack_bf16_2(w1.z, w1.w);
        bfrag[c] = p.f;
    }
    frag_ab bias_b;
    {
        ABPack p; p.u[0] = p.u[1] = p.u[2] = p.u[3] = 0;
        if (hb == 0) {
            const float* bp2 = bias + col * 16 + j0;
            float4 w0 = *(const float4*)bp2;
            float4 w1 = *(const float4*)(bp2 + 4);
            p.u[0] = pack_bf16_2(w0.x, w0.y);
            p.u[1] = pack_bf16_2(w0.z, w0.w);
            p.u[2] = pack_bf16_2(w1.x, w1.y);
            p.u[3] = pack_bf16_2(w1.z, w1.w);
        }
        bias_b = p.f;
    }

    for (int g = g0; g < g1; ++g) {
        const int eb = g << 4;
        const int e  = eb + col;
        const int ec = min(e, n_edges - 1);

        const int2 pr = ((const int2*)pair)[ec];            // x=dst, y=src

        // fused rank: only quad 0 increments; slot broadcast later via shfl
        int slot = -1;
        if (quad == 0 && e < n_edges) {
            int r = atomicAdd(&counts[pr.x], 1);
            if (r < CAP) {
                slot = pr.x * CAP + r;
            } else {
                int oi = atomicAdd(oflow_cnt, 1);
                if (oi < OFLOW_CAP) oflow[oi] = e;
            }
        }

        // neigh slice: chunk-invariant 8 floats [j0, j0+8)
        const float* np_ = atom + (size_t)pr.y * DIM + j0;
        float4 n0 = *(const float4*)np_;
        float4 n1 = *(const float4*)(np_ + 4);
        float nb[8] = {n0.x, n0.y, n0.z, n0.w, n1.x, n1.y, n1.z, n1.w};

        const float4* bp = (const float4*)(bond + (size_t)ec * DIM);
        float4 b0 = bp[0], b1 = bp[1], b2 = bp[2], b3 = bp[3];
        float bv[16] = {b0.x, b0.y, b0.z, b0.w, b1.x, b1.y, b1.z, b1.w,
                        b2.x, b2.y, b2.z, b2.w, b3.x, b3.y, b3.z, b3.w};

        frag_cd acc = {0.f, 0.f, 0.f, 0.f};
#pragma unroll
        for (int c = 0; c < 8; ++c) {
            const float bk = bv[2 * c + hb];
            ABPack a;
            a.u[0] = pack_bf16_2(bk * nb[0], bk * nb[1]);
            a.u[1] = pack_bf16_2(bk * nb[2], bk * nb[3]);
            a.u[2] = pack_bf16_2(bk * nb[4], bk * nb[5]);
            a.u[3] = pack_bf16_2(bk * nb[6], bk * nb[7]);
            acc = __builtin_amdgcn_mfma_f32_16x16x32_bf16(a.f, bfrag[c], acc, 0, 0, 0);
        }
        { // bias chunk
            ABPack a; a.u[0] = a.u[1] = a.u[2] = a.u[3] = 0;
            if (hb == 0) {
                a.u[0] = pack_bf16_2(nb[0], nb[1]);
                a.u[1] = pack_bf16_2(nb[2], nb[3]);
                a.u[2] = pack_bf16_2(nb[4], nb[5]);
                a.u[3] = pack_bf16_2(nb[6], nb[7]);
            }
            acc = __builtin_amdgcn_mfma_f32_16x16x32_bf16(a.f, bias_b, acc, 0, 0, 0);
        }

        // D: lane (quad,col) holds rows m=quad*4+r at output col. slot in lane m.
#pragma unroll
        for (int r = 0; r < 4; ++r) {
            const int m = quad * 4 + r;
            const int s = __shfl(slot, m, 64);
            if (s >= 0)
                msgs[(size_t)s * DIM + col] = (uint16_t)(__float_as_uint(acc[r]) >> 16);
        }
    }
}

// ---- reduce: 8 threads/atom over fixed-stride bf16 slots, atomic-free
__global__ __launch_bounds__(256) void reduce_kernel(
    const uint16_t* __restrict__ msgs, const int* __restrict__ counts,
    float* __restrict__ out, int n_atoms)
{
    int t = blockIdx.x * blockDim.x + threadIdx.x;
    int a = t >> 3;
    if (a >= n_atoms) return;
    int c    = t & 3;          // 4-col chunk
    int half = (t >> 2) & 1;   // split message list

    int cnt = min(counts[a], CAP);
    const uint32_t* base = (const uint32_t*)(msgs + (size_t)a * CAP * DIM);

    float4 acc = make_float4(0.f, 0.f, 0.f, 0.f);
    for (int j = half; j < cnt; j += 2) {
        uint2 v = *(const uint2*)(base + j * 8 + c * 2);     // 4 bf16 = 8 B
        acc.x += __uint_as_float(v.x << 16);
        acc.y += __uint_as_float(v.x & 0xFFFF0000u);
        acc.z += __uint_as_float(v.y << 16);
        acc.w += __uint_as_float(v.y & 0xFFFF0000u);
    }
    acc.x += __shfl_xor(acc.x, 4);
    acc.y += __shfl_xor(acc.y, 4);
    acc.z += __shfl_xor(acc.z, 4);
    acc.w += __shfl_xor(acc.w, 4);
    if (half == 0)
        ((float4*)(out + (size_t)a * DIM))[c] = acc;
}

// ---- overflow fix-up: scalar f32 math + atomicAdd; runs AFTER reduce.
// Normally *oflow_cnt == 0 -> immediate exit (~2us launch).
__global__ __launch_bounds__(256) void oflow_kernel(
    const float* __restrict__ atom, const float* __restrict__ bond,
    const int*   __restrict__ pair, const float* __restrict__ kern,
    const float* __restrict__ bias,
    const int* __restrict__ oflow_cnt, const int* __restrict__ oflow,
    float* __restrict__ out, int n_edges)
{
    int n = min(*oflow_cnt, OFLOW_CAP);
    for (int i = blockIdx.x * blockDim.x + threadIdx.x; i < n;
         i += gridDim.x * blockDim.x) {
        int e   = oflow[i];
        int dst = pair[2 * e + 0];
        int src = pair[2 * e + 1];
        float neigh[DIM], bnd[DIM], acc[DIM];
        for (int q = 0; q < DIM; ++q) neigh[q] = atom[(size_t)src * DIM + q];
        for (int q = 0; q < DIM; ++q) bnd[q]   = bond[(size_t)e * DIM + q];
#pragma unroll
        for (int ii = 0; ii < DIM; ++ii) {
            float d = 0.f;
#pragma unroll
            for (int j = 0; j < DIM; ++j) d = fmaf(bias[ii * DIM + j], neigh[j], d);
            acc[ii] = d;
        }
#pragma unroll 1
        for (int k = 0; k < DIM; ++k) {
            const float bk = bnd[k];
            const float* Kr = kern + k * (DIM * DIM);
#pragma unroll
            for (int ii = 0; ii < DIM; ++ii) {
                float d = 0.f;
#pragma unroll
                for (int j = 0; j < DIM; ++j) d = fmaf(Kr[ii * DIM + j], neigh[j], d);
                acc[ii] = fmaf(bk, d, acc[ii]);
            }
        }
#pragma unroll
        for (int ii = 0; ii < DIM; ++ii) atomicAdd(&out[(size_t)dst * DIM + ii], acc[ii]);
    }
}

// ---- safety fallback if ws too small (round-1 structure)
__global__ __launch_bounds__(256) void edge_atomic_kernel(
    const float* __restrict__ atom, const float* __restrict__ bond,
    const int*   __restrict__ pair, const float* __restrict__ kern,
    const float* __restrict__ bias, float* __restrict__ out, int n_edges)
{
    int e = blockIdx.x * blockDim.x + threadIdx.x;
    if (e >= n_edges) return;
    int dst = pair[2 * e + 0];
    int src = pair[2 * e + 1];
    float neigh[DIM], bnd[DIM], acc[DIM];
    for (int q = 0; q < DIM; ++q) neigh[q] = atom[(size_t)src * DIM + q];
    for (int q = 0; q < DIM; ++q) bnd[q]   = bond[(size_t)e * DIM + q];
#pragma unroll
    for (int i = 0; i < DIM; ++i) {
        float d = 0.f;
#pragma unroll
        for (int j = 0; j < DIM; ++j) d = fmaf(bias[i * DIM + j], neigh[j], d);
        acc[i] = d;
    }
#pragma unroll 1
    for (int k = 0; k < DIM; ++k) {
        const float bk = bnd[k];
        const float* Kr = kern + k * (DIM * DIM);
#pragma unroll
        for (int i = 0; i < DIM; ++i) {
            float d = 0.f;
#pragma unroll
            for (int j = 0; j < DIM; ++j) d = fmaf(Kr[i * DIM + j], neigh[j], d);
            acc[i] = fmaf(bk, d, acc[i]);
        }
    }
#pragma unroll
    for (int i = 0; i < DIM; ++i) atomicAdd(&out[(size_t)dst * DIM + i], acc[i]);
}

extern "C" void kernel_launch(void* const* d_in, const int* in_sizes, int n_in,
                              void* d_out, int out_size, void* d_ws, size_t ws_size,
                              hipStream_t stream)
{
    const float* atom = (const float*)d_in[0];   // (20000,16) f32
    const float* bond = (const float*)d_in[1];   // (640000,16) f32
    const int*   pair = (const int*)d_in[2];     // (640000,2) i32 [dst, src]
    const float* kern = (const float*)d_in[3];   // (16,256) f32
    const float* bias = (const float*)d_in[4];   // (256,) f32
    float*       out  = (float*)d_out;           // (20000,16) f32

    const int n_edges = in_sizes[1] / DIM;       // 640000
    const int n_atoms = in_sizes[0] / DIM;       // 20000

    // ws: counts[n_atoms] | oflow_cnt[1] | oflow[OFLOW_CAP] | align64 | msgs bf16
    size_t counts_off = 0;
    size_t ocnt_off   = counts_off + (size_t)n_atoms * sizeof(int);
    size_t oflow_off  = ocnt_off + sizeof(int);
    size_t msgs_off   = (oflow_off + (size_t)OFLOW_CAP * sizeof(int) + 63) & ~(size_t)63;
    size_t needed     = msgs_off + (size_t)n_atoms * CAP * DIM * sizeof(uint16_t);

    const int threads = 256;

    if (ws_size >= needed) {
        int*      counts    = (int*)((char*)d_ws + counts_off);
        int*      oflow_cnt = (int*)((char*)d_ws + ocnt_off);
        int*      oflow     = (int*)((char*)d_ws + oflow_off);
        uint16_t* msgs      = (uint16_t*)((char*)d_ws + msgs_off);

        // zero counts + oflow counter in one memset (contiguous)
        hipMemsetAsync(counts, 0, (size_t)(n_atoms + 1) * sizeof(int), stream);

        const int n_groups = (n_edges + 15) / 16;
        const int waves    = (n_groups + GPW - 1) / GPW;
        const int mblocks  = (waves * 64 + threads - 1) / threads;
        msg_mfma_kernel<<<mblocks, threads, 0, stream>>>(
            atom, bond, pair, kern, bias, counts, oflow_cnt, oflow, msgs,
            n_edges, n_groups);

        const int rthreads = n_atoms * 8;
        reduce_kernel<<<(rthreads + threads - 1) / threads, threads, 0, stream>>>(
            msgs, counts, out, n_atoms);

        oflow_kernel<<<8, threads, 0, stream>>>(
            atom, bond, pair, kern, bias, oflow_cnt, oflow, out, n_edges);
    } else {
        hipMemsetAsync(out, 0, (size_t)out_size * sizeof(float), stream);
        edge_atomic_kernel<<<(n_edges + threads - 1) / threads, threads, 0, stream>>>(
            atom, bond, pair, kern, bias, out, n_edges);
    }
}

// Round 5
// 146.561 us; speedup vs baseline: 4.7531x; 1.0244x over previous
//
#include <hip/hip_runtime.h>
#include <stdint.h>

// EdgeNetwork, round 5: operand-swapped MFMA (D = W^T Z^T = msgs^T layout)
// so each lane stores ONE packed 8B chunk (4 bf16 cols) per group, instead of
// four scattered 2B stores + 4 shfls. counts padded to 64B stride to cut
// atomic line contention (r4: 512 atomics/line -> 32).
// History: r1 630us (f32 atomic write-through) -> r2 CSR 333 -> r3 MFMA 190
// -> r4 fused-rank binning 150 (msg regressed 55->66: atomic in critical path,
// 2B store storm) -> r5: fix the store path + contention.

constexpr int DIM  = 16;
constexpr int CAP  = 64;     // slots per atom; P(deg>64) ~ 1e-8 at Poisson(32)
constexpr int CSTR = 16;     // counts stride (ints) = one 64B line per atom
constexpr int OFLOW_CAP = 65536;
constexpr int GPW  = 4;      // 16-edge groups per wave, fully unrolled

using frag_ab = __attribute__((ext_vector_type(8))) short;   // 8 bf16
using frag_cd = __attribute__((ext_vector_type(4))) float;   // 4 f32
union ABPack { frag_ab f; uint32_t u[4]; };

__device__ __forceinline__ uint32_t pack_bf16_2(float lo, float hi) {
    // one v_perm_b32: truncate-to-bf16 pair, lo in low 16 bits
    return __builtin_amdgcn_perm(__float_as_uint(hi), __float_as_uint(lo), 0x07060302u);
}

// ---- msg kernel: fused rank + MFMA(T) + packed bf16 store into stride slot
__global__ __launch_bounds__(256) void msg_mfma_kernel(
    const float* __restrict__ atom, const float* __restrict__ bond,
    const int*   __restrict__ pair, const float* __restrict__ kern,
    const float* __restrict__ bias,
    int* __restrict__ counts, int* __restrict__ oflow_cnt, int* __restrict__ oflow,
    uint16_t* __restrict__ msgs, int n_edges, int n_groups)
{
    const int wave = (int)((blockIdx.x * blockDim.x + threadIdx.x) >> 6);
    const int lane = threadIdx.x & 63;
    const int g0 = wave * GPW;
    if (g0 >= n_groups) return;

    const int col  = lane & 15;        // A(W): output row i | B(Z): edge e | D: col e
    const int quad = lane >> 4;        // 0..3
    const int hb   = quad >> 1;        // kb parity within chunk
    const int j0   = (quad & 1) * 8;   // neigh sub-range

    // W fragments as operand-0 (A[m=i][k]); identical loads to r3/r4 (verified)
    frag_ab wfrag[8];
#pragma unroll
    for (int c = 0; c < 8; ++c) {
        const float* wp = kern + (2 * c + hb) * 256 + col * 16 + j0;
        float4 w0 = *(const float4*)wp;
        float4 w1 = *(const float4*)(wp + 4);
        ABPack p;
        p.u[0] = pack_bf16_2(w0.x, w0.y);
        p.u[1] = pack_bf16_2(w0.z, w0.w);
        p.u[2] = pack_bf16_2(w1.x, w1.y);
        p.u[3] = pack_bf16_2(w1.z, w1.w);
        wfrag[c] = p.f;
    }
    frag_ab bias_a;
    {
        ABPack p; p.u[0] = p.u[1] = p.u[2] = p.u[3] = 0;
        if (hb == 0) {
            const float* bp2 = bias + col * 16 + j0;
            float4 w0 = *(const float4*)bp2;
            float4 w1 = *(const float4*)(bp2 + 4);
            p.u[0] = pack_bf16_2(w0.x, w0.y);
            p.u[1] = pack_bf16_2(w0.z, w0.w);
            p.u[2] = pack_bf16_2(w1.x, w1.y);
            p.u[3] = pack_bf16_2(w1.z, w1.w);
        }
        bias_a = p.f;
    }

#pragma unroll
    for (int u = 0; u < GPW; ++u) {
        const int g = g0 + u;
        if (g < n_groups) {
            const int eb = g << 4;
            const int e  = eb + col;
            const int ec = min(e, n_edges - 1);

            const int2 pr = ((const int2*)pair)[ec];        // x=dst, y=src

            // fused rank: quad 0 lanes only; 64B-strided counters
            int slot = -1;
            if (quad == 0 && e < n_edges) {
                int r = atomicAdd(&counts[pr.x * CSTR], 1);
                if (r < CAP) {
                    slot = pr.x * CAP + r;
                } else {
                    int oi = atomicAdd(oflow_cnt, 1);
                    if (oi < OFLOW_CAP) oflow[oi] = e;
                }
            }

            // neigh slice [j0, j0+8) for this lane's edge
            const float* np_ = atom + (size_t)pr.y * DIM + j0;
            float4 n0 = *(const float4*)np_;
            float4 n1 = *(const float4*)(np_ + 4);
            float nb[8] = {n0.x, n0.y, n0.z, n0.w, n1.x, n1.y, n1.z, n1.w};

            const float4* bp = (const float4*)(bond + (size_t)ec * DIM);
            float4 b0 = bp[0], b1 = bp[1], b2 = bp[2], b3 = bp[3];
            float bv[16] = {b0.x, b0.y, b0.z, b0.w, b1.x, b1.y, b1.z, b1.w,
                            b2.x, b2.y, b2.z, b2.w, b3.x, b3.y, b3.z, b3.w};

            frag_cd acc = {0.f, 0.f, 0.f, 0.f};
#pragma unroll
            for (int c = 0; c < 8; ++c) {
                const float bk = bv[2 * c + hb];
                ABPack z;
                z.u[0] = pack_bf16_2(bk * nb[0], bk * nb[1]);
                z.u[1] = pack_bf16_2(bk * nb[2], bk * nb[3]);
                z.u[2] = pack_bf16_2(bk * nb[4], bk * nb[5]);
                z.u[3] = pack_bf16_2(bk * nb[6], bk * nb[7]);
                // operand swap vs r4: D = W^T Z^T -> lane holds 4 consecutive cols
                acc = __builtin_amdgcn_mfma_f32_16x16x32_bf16(wfrag[c], z.f, acc, 0, 0, 0);
            }
            { // bias chunk (k<16 half only)
                ABPack z; z.u[0] = z.u[1] = z.u[2] = z.u[3] = 0;
                if (hb == 0) {
                    z.u[0] = pack_bf16_2(nb[0], nb[1]);
                    z.u[1] = pack_bf16_2(nb[2], nb[3]);
                    z.u[2] = pack_bf16_2(nb[4], nb[5]);
                    z.u[3] = pack_bf16_2(nb[6], nb[7]);
                }
                acc = __builtin_amdgcn_mfma_f32_16x16x32_bf16(bias_a, z.f, acc, 0, 0, 0);
            }

            // D^T: lane (quad,col) holds msgs[e=col][i=quad*4 .. +3]
            const int s = __shfl(slot, col, 64);   // from quad0 lane `col`
            if (s >= 0) {
                uint2 pkd;
                pkd.x = pack_bf16_2(acc[0], acc[1]);
                pkd.y = pack_bf16_2(acc[2], acc[3]);
                *(uint2*)(msgs + (size_t)s * DIM + quad * 4) = pkd;  // one 8B store
            }
        }
    }
}

// ---- reduce: 8 threads/atom over fixed-stride bf16 slots, atomic-free
__global__ __launch_bounds__(256) void reduce_kernel(
    const uint16_t* __restrict__ msgs, const int* __restrict__ counts,
    float* __restrict__ out, int n_atoms)
{
    int t = blockIdx.x * blockDim.x + threadIdx.x;
    int a = t >> 3;
    if (a >= n_atoms) return;
    int c    = t & 3;          // 4-col chunk
    int half = (t >> 2) & 1;   // split message list

    int cnt = min(counts[a * CSTR], CAP);
    const uint32_t* base = (const uint32_t*)(msgs + (size_t)a * CAP * DIM);

    float4 acc = make_float4(0.f, 0.f, 0.f, 0.f);
    for (int j = half; j < cnt; j += 2) {
        uint2 v = *(const uint2*)(base + j * 8 + c * 2);     // 4 bf16 = 8 B
        acc.x += __uint_as_float(v.x << 16);
        acc.y += __uint_as_float(v.x & 0xFFFF0000u);
        acc.z += __uint_as_float(v.y << 16);
        acc.w += __uint_as_float(v.y & 0xFFFF0000u);
    }
    acc.x += __shfl_xor(acc.x, 4);
    acc.y += __shfl_xor(acc.y, 4);
    acc.z += __shfl_xor(acc.z, 4);
    acc.w += __shfl_xor(acc.w, 4);
    if (half == 0)
        ((float4*)(out + (size_t)a * DIM))[c] = acc;
}

// ---- overflow fix-up (normally 0 edges): scalar f32 + atomicAdd, AFTER reduce
__global__ __launch_bounds__(256) void oflow_kernel(
    const float* __restrict__ atom, const float* __restrict__ bond,
    const int*   __restrict__ pair, const float* __restrict__ kern,
    const float* __restrict__ bias,
    const int* __restrict__ oflow_cnt, const int* __restrict__ oflow,
    float* __restrict__ out, int n_edges)
{
    int n = min(*oflow_cnt, OFLOW_CAP);
    for (int i = blockIdx.x * blockDim.x + threadIdx.x; i < n;
         i += gridDim.x * blockDim.x) {
        int e   = oflow[i];
        int dst = pair[2 * e + 0];
        int src = pair[2 * e + 1];
        float neigh[DIM], bnd[DIM], acc[DIM];
        for (int q = 0; q < DIM; ++q) neigh[q] = atom[(size_t)src * DIM + q];
        for (int q = 0; q < DIM; ++q) bnd[q]   = bond[(size_t)e * DIM + q];
#pragma unroll
        for (int ii = 0; ii < DIM; ++ii) {
            float d = 0.f;
#pragma unroll
            for (int j = 0; j < DIM; ++j) d = fmaf(bias[ii * DIM + j], neigh[j], d);
            acc[ii] = d;
        }
#pragma unroll 1
        for (int k = 0; k < DIM; ++k) {
            const float bk = bnd[k];
            const float* Kr = kern + k * (DIM * DIM);
#pragma unroll
            for (int ii = 0; ii < DIM; ++ii) {
                float d = 0.f;
#pragma unroll
                for (int j = 0; j < DIM; ++j) d = fmaf(Kr[ii * DIM + j], neigh[j], d);
                acc[ii] = fmaf(bk, d, acc[ii]);
            }
        }
#pragma unroll
        for (int ii = 0; ii < DIM; ++ii) atomicAdd(&out[(size_t)dst * DIM + ii], acc[ii]);
    }
}

// ---- safety fallback if ws too small (round-1 structure)
__global__ __launch_bounds__(256) void edge_atomic_kernel(
    const float* __restrict__ atom, const float* __restrict__ bond,
    const int*   __restrict__ pair, const float* __restrict__ kern,
    const float* __restrict__ bias, float* __restrict__ out, int n_edges)
{
    int e = blockIdx.x * blockDim.x + threadIdx.x;
    if (e >= n_edges) return;
    int dst = pair[2 * e + 0];
    int src = pair[2 * e + 1];
    float neigh[DIM], bnd[DIM], acc[DIM];
    for (int q = 0; q < DIM; ++q) neigh[q] = atom[(size_t)src * DIM + q];
    for (int q = 0; q < DIM; ++q) bnd[q]   = bond[(size_t)e * DIM + q];
#pragma unroll
    for (int i = 0; i < DIM; ++i) {
        float d = 0.f;
#pragma unroll
        for (int j = 0; j < DIM; ++j) d = fmaf(bias[i * DIM + j], neigh[j], d);
        acc[i] = d;
    }
#pragma unroll 1
    for (int k = 0; k < DIM; ++k) {
        const float bk = bnd[k];
        const float* Kr = kern + k * (DIM * DIM);
#pragma unroll
        for (int i = 0; i < DIM; ++i) {
            float d = 0.f;
#pragma unroll
            for (int j = 0; j < DIM; ++j) d = fmaf(Kr[i * DIM + j], neigh[j], d);
            acc[i] = fmaf(bk, d, acc[i]);
        }
    }
#pragma unroll
    for (int i = 0; i < DIM; ++i) atomicAdd(&out[(size_t)dst * DIM + i], acc[i]);
}

extern "C" void kernel_launch(void* const* d_in, const int* in_sizes, int n_in,
                              void* d_out, int out_size, void* d_ws, size_t ws_size,
                              hipStream_t stream)
{
    const float* atom = (const float*)d_in[0];   // (20000,16) f32
    const float* bond = (const float*)d_in[1];   // (640000,16) f32
    const int*   pair = (const int*)d_in[2];     // (640000,2) i32 [dst, src]
    const float* kern = (const float*)d_in[3];   // (16,256) f32
    const float* bias = (const float*)d_in[4];   // (256,) f32
    float*       out  = (float*)d_out;           // (20000,16) f32

    const int n_edges = in_sizes[1] / DIM;       // 640000
    const int n_atoms = in_sizes[0] / DIM;       // 20000

    // ws: counts[n_atoms*CSTR] | oflow_cnt[1] | oflow[OFLOW_CAP] | 64B | msgs bf16
    size_t counts_off = 0;
    size_t ocnt_off   = counts_off + (size_t)n_atoms * CSTR * sizeof(int);
    size_t oflow_off  = ocnt_off + sizeof(int);
    size_t msgs_off   = (oflow_off + (size_t)OFLOW_CAP * sizeof(int) + 63) & ~(size_t)63;
    size_t needed     = msgs_off + (size_t)n_atoms * CAP * DIM * sizeof(uint16_t);

    const int threads = 256;

    if (ws_size >= needed) {
        int*      counts    = (int*)((char*)d_ws + counts_off);
        int*      oflow_cnt = (int*)((char*)d_ws + ocnt_off);
        int*      oflow     = (int*)((char*)d_ws + oflow_off);
        uint16_t* msgs      = (uint16_t*)((char*)d_ws + msgs_off);

        // zero counts (padded) + oflow counter in one contiguous memset
        hipMemsetAsync(counts, 0, (size_t)n_atoms * CSTR * sizeof(int) + sizeof(int),
                       stream);

        const int n_groups = (n_edges + 15) / 16;
        const int waves    = (n_groups + GPW - 1) / GPW;
        const int mblocks  = (waves * 64 + threads - 1) / threads;
        msg_mfma_kernel<<<mblocks, threads, 0, stream>>>(
            atom, bond, pair, kern, bias, counts, oflow_cnt, oflow, msgs,
            n_edges, n_groups);

        const int rthreads = n_atoms * 8;
        reduce_kernel<<<(rthreads + threads - 1) / threads, threads, 0, stream>>>(
            msgs, counts, out, n_atoms);

        oflow_kernel<<<8, threads, 0, stream>>>(
            atom, bond, pair, kern, bias, oflow_cnt, oflow, out, n_edges);
    } else {
        hipMemsetAsync(out, 0, (size_t)out_size * sizeof(float), stream);
        edge_atomic_kernel<<<(n_edges + threads - 1) / threads, threads, 0, stream>>>(
            atom, bond, pair, kern, bias, out, n_edges);
    }
}